// Round 5
// baseline (619.212 us; speedup 1.0000x reference)
//
#include <hip/hip_runtime.h>
#include <stdint.h>

#define T_TOK 2048
#define DIM   1024
#define HID   4096
#define NEXP  8

typedef __attribute__((ext_vector_type(8))) short  short8;
typedef __attribute__((ext_vector_type(4))) short  short4v;
typedef __attribute__((ext_vector_type(4))) float  floatx4;
typedef __attribute__((ext_vector_type(4))) int    intx4;

__device__ __forceinline__ ushort f2bf(float f) {
    union { float f; uint32_t i; } v; v.f = f;
    uint32_t r = v.i + 0x7FFFu + ((v.i >> 16) & 1u);
    return (ushort)(r >> 16);
}
__device__ __forceinline__ float gelu_exact(float x) {
    return 0.5f * x * (1.0f + erff(x * 0.70710678118654752f));
}

// ------------------------------------------------- x (fp32) -> bf16 Xb
__global__ __launch_bounds__(256) void cast_x_kernel(
    const float* __restrict__ x, ushort* __restrict__ Xb)
{
    int i = (blockIdx.x * 256 + threadIdx.x) * 8;
    floatx4 a = *(const floatx4*)(x + i);
    floatx4 b = *(const floatx4*)(x + i + 4);
    uint32_t o[4];
    o[0] = (uint32_t)f2bf(a[0]) | ((uint32_t)f2bf(a[1]) << 16);
    o[1] = (uint32_t)f2bf(a[2]) | ((uint32_t)f2bf(a[3]) << 16);
    o[2] = (uint32_t)f2bf(b[0]) | ((uint32_t)f2bf(b[1]) << 16);
    o[3] = (uint32_t)f2bf(b[2]) | ((uint32_t)f2bf(b[3]) << 16);
    *(intx4*)(Xb + i) = *(const intx4*)o;
}

// ------------------------------------------------- router (fp32)
// One wave/token; 8 len-1024 dots; butterfly reduce; top-2 via sigmoid of
// logit gap (== softmax->top2->renorm).
__global__ __launch_bounds__(256) void router_kernel(
    const float* __restrict__ x, const float* __restrict__ Wr,
    const float* __restrict__ br, int* __restrict__ counts,
    int* __restrict__ tlist, float* __restrict__ wlist)
{
    int wv = threadIdx.x >> 6, l = threadIdx.x & 63;
    int t = blockIdx.x * 4 + wv;
    float acc[NEXP];
#pragma unroll
    for (int e = 0; e < NEXP; e++) acc[e] = 0.f;
    const float* xr = x + (size_t)t * DIM;
    for (int d = l; d < DIM; d += 64) {
        float xv = xr[d];
        floatx4 w0 = *(const floatx4*)(Wr + (size_t)d * NEXP);
        floatx4 w1 = *(const floatx4*)(Wr + (size_t)d * NEXP + 4);
#pragma unroll
        for (int e = 0; e < 4; e++) { acc[e] += xv * w0[e]; acc[e + 4] += xv * w1[e]; }
    }
#pragma unroll
    for (int e = 0; e < NEXP; e++) {
#pragma unroll
        for (int off = 32; off; off >>= 1) acc[e] += __shfl_xor(acc[e], off, 64);
    }
    if (l == 0) {
        float lg[NEXP];
#pragma unroll
        for (int e = 0; e < NEXP; e++) lg[e] = acc[e] + br[e];
        int e0 = 0;
#pragma unroll
        for (int e = 1; e < NEXP; e++) if (lg[e] > lg[e0]) e0 = e;
        int e1 = -1;
#pragma unroll
        for (int e = 0; e < NEXP; e++) {
            if (e == e0) continue;
            if (e1 < 0 || lg[e] > lg[e1]) e1 = e;
        }
        float w0 = 1.f / (1.f + expf(lg[e1] - lg[e0]));
        float w1 = 1.f - w0;
        int s0 = atomicAdd(&counts[e0], 1);
        tlist[e0 * T_TOK + s0] = t;
        wlist[e0 * T_TOK + s0] = w0;
        int s1 = atomicAdd(&counts[e1], 1);
        tlist[e1 * T_TOK + s1] = t | (1 << 16);
        wlist[e1 * T_TOK + s1] = w1;
    }
}

// ------------------------------------------------- grouped GEMM
// MODE 0: H[tok*2+rk] = gelu(Xb_g @ bf16(W1[e]) + b1)   M=Ne, N=4096, K=1024
// MODE 1: Yacc[tok] += w*(H_g @ bf16(W2[e]) + b2)       M=Ne, N=1024, K=2048 (x2 kc)
// 128x128 tile, 4 waves, BK=32, mfma_f32_16x16x32_bf16.
// A: per-lane global_load_dwordx4 -> ds_write_b128, [r][k] stride 40 (pad).
// B: fp32 float4 loads -> bf16 pack -> LDS [n][k] transposed, stride 36.
template <int MODE>
__global__ __launch_bounds__(256, 2) void moe_gemm(
    const ushort* __restrict__ A, const float* __restrict__ W,
    const float* __restrict__ bias, const int* __restrict__ counts,
    const int* __restrict__ tlist, const float* __restrict__ wlist,
    ushort* __restrict__ Hout, float* __restrict__ Yacc)
{
    constexpr int NTOT = MODE ? DIM : HID;
    constexpr int AROW = MODE ? HID : DIM;
    constexpr int KLEN = MODE ? 2048 : 1024;

    int bx = blockIdx.x;
    int e, mt, nt, kc;
    if (MODE == 0) { e = bx >> 9; mt = (bx >> 5) & 15; nt = bx & 31; kc = 0; }
    else { e = bx >> 8; int r = bx & 255; mt = r >> 4; nt = (r >> 1) & 7; kc = r & 1; }

    int Ne = counts[e];
    if (mt * 128 >= Ne) return;

    size_t wbase = (size_t)e * DIM * HID + (size_t)kc * 2048 * NTOT + (size_t)nt * 128;

    __shared__ ushort ldsA[128 * 40];  // 10KB, [r][k] pad-40 (2-way banks: free)
    __shared__ ushort ldsB[128 * 36];  // 9KB,  [n][k] transposed, stride 36

    int tid = threadIdx.x;
    int wv = tid >> 6, l = tid & 63;

    // --- A staging: idx = i*256+tid covers 128 rows x 4 chunks of 8 ---
    const ushort* arowp[2]; int apos[2];
#pragma unroll
    for (int i = 0; i < 2; i++) {
        int idx = i * 256 + tid;
        int r = idx >> 2, p = idx & 3;
        int slot = mt * 128 + r; if (slot >= Ne) slot = Ne - 1;
        int packed = tlist[e * T_TOK + slot];
        int tok = packed & 0xFFFF, rk = (packed >> 16) & 1;
        size_t arow = MODE ? (size_t)(tok * 2 + rk) : (size_t)tok;
        arowp[i] = A + arow * AROW + (MODE ? kc * 2048 : 0) + p * 8;
        apos[i] = r * 40 + p * 8;
    }

    // --- B staging: thread (kp = k-pair, n8 = n-chunk of 8) ---
    int kp = tid & 15;
    int n8 = tid >> 4;
    size_t boffg = wbase + (size_t)(2 * kp) * NTOT + n8 * 8;

    // --- fragment offsets ---
    int wm = wv >> 1, wn = wv & 1;
    int q = l >> 4;
    int aoff[4], boff[4];
#pragma unroll
    for (int mi = 0; mi < 4; mi++)
        aoff[mi] = (wm * 64 + mi * 16 + (l & 15)) * 40 + q * 8;
#pragma unroll
    for (int ni = 0; ni < 4; ni++)
        boff[ni] = (wn * 64 + ni * 16 + (l & 15)) * 36 + q * 8;

    floatx4 zz = {0.f, 0.f, 0.f, 0.f};
    floatx4 acc[4][4];
#pragma unroll
    for (int mi = 0; mi < 4; mi++)
#pragma unroll
        for (int ni = 0; ni < 4; ni++) acc[mi][ni] = zz;

    for (int k0 = 0; k0 < KLEN; k0 += 32) {
        // global loads (latency overlaps previous iteration's MFMAs)
        intx4 av[2];
#pragma unroll
        for (int i = 0; i < 2; i++) av[i] = *(const intx4*)(arowp[i] + k0);
        const float* p0 = W + boffg + (size_t)k0 * NTOT;
        const float* p1 = p0 + NTOT;
        floatx4 a0 = *(const floatx4*)(p0);
        floatx4 a1 = *(const floatx4*)(p0 + 4);
        floatx4 b0 = *(const floatx4*)(p1);
        floatx4 b1 = *(const floatx4*)(p1 + 4);
        uint32_t pr[8];
#pragma unroll
        for (int j = 0; j < 8; j++) {
            float va = (j < 4) ? a0[j & 3] : a1[j & 3];
            float vb = (j < 4) ? b0[j & 3] : b1[j & 3];
            pr[j] = (uint32_t)f2bf(va) | ((uint32_t)f2bf(vb) << 16);
        }

        __syncthreads();   // previous iteration's fragment reads complete
#pragma unroll
        for (int i = 0; i < 2; i++) *(intx4*)&ldsA[apos[i]] = av[i];
#pragma unroll
        for (int j = 0; j < 8; j++)
            *(uint32_t*)&ldsB[(n8 * 8 + j) * 36 + 2 * kp] = pr[j];
        __syncthreads();   // staging visible

        short8 af[4], bf[4];
#pragma unroll
        for (int mi = 0; mi < 4; mi++) af[mi] = *(const short8*)&ldsA[aoff[mi]];
#pragma unroll
        for (int ni = 0; ni < 4; ni++) {
            short4v blo = *(const short4v*)&ldsB[boff[ni]];
            short4v bhi = *(const short4v*)&ldsB[boff[ni] + 4];
            bf[ni] = __builtin_shufflevector(blo, bhi, 0, 1, 2, 3, 4, 5, 6, 7);
        }
#pragma unroll
        for (int mi = 0; mi < 4; mi++)
#pragma unroll
            for (int ni = 0; ni < 4; ni++)
                acc[mi][ni] = __builtin_amdgcn_mfma_f32_16x16x32_bf16(
                    af[mi], bf[ni], acc[mi][ni], 0, 0, 0);
    }

    // --- epilogue: C/D col=lane&15, row=quad*4+reg ---
#pragma unroll
    for (int mi = 0; mi < 4; mi++) {
        int rbase = wm * 64 + mi * 16 + q * 4;
#pragma unroll
        for (int j = 0; j < 4; j++) {
            int slot = mt * 128 + rbase + j;
            if (slot >= Ne) continue;   // pad rows: must skip (atomicAdd!)
            int packed = tlist[e * T_TOK + slot];
            int tok = packed & 0xFFFF, rk = (packed >> 16) & 1;
#pragma unroll
            for (int ni = 0; ni < 4; ni++) {
                int col = nt * 128 + wn * 64 + ni * 16 + (l & 15);
                float v = acc[mi][ni][j];
                float bc = bias[e * NTOT + col];
                if (MODE == 0) {
                    v = gelu_exact(v + bc);
                    Hout[(size_t)(tok * 2 + rk) * HID + col] = f2bf(v);
                } else {
                    if (kc == 0) v += bc;   // per-(t,e) bias, weighted below
                    v *= wlist[e * T_TOK + slot];
                    atomicAdd(&Yacc[(size_t)tok * DIM + col], v);
                }
            }
        }
    }
}

// ------------------------------------------------- combine: fp32 passthrough
// Output dtype = reference output dtype = float32 (R0-R4 post-mortem).
__global__ __launch_bounds__(256) void combine_kernel(
    const float* __restrict__ Y, float* __restrict__ out)
{
    int i = (blockIdx.x * 256 + threadIdx.x) * 4;
    *(floatx4*)(out + i) = *(const floatx4*)(Y + i);
}

// ------------------------------------------------- launch
extern "C" void kernel_launch(void* const* d_in, const int* in_sizes, int n_in,
                              void* d_out, int out_size, void* d_ws, size_t ws_size,
                              hipStream_t stream) {
    const float* x  = (const float*)d_in[0];
    const float* Wr = (const float*)d_in[1];
    const float* br = (const float*)d_in[2];
    const float* W1 = (const float*)d_in[3];
    const float* b1 = (const float*)d_in[4];
    const float* W2 = (const float*)d_in[5];
    const float* b2 = (const float*)d_in[6];
    float* out = (float*)d_out;

    // workspace layout (42.07 MB total — proven safe in R2..R4)
    char* ws = (char*)d_ws;
    int*    counts = (int*)ws;                                   // 32 B
    int*    tlist  = (int*)(ws + 256);                           // 64 KB
    float*  wlist  = (float*)(ws + 256 + 65536);                 // 64 KB
    ushort* Hbuf   = (ushort*)(ws + 256 + 131072);               // 33.55 MB
    float*  Yacc   = (float*)(ws + 256 + 131072 + 33554432);     // 8.39 MB
    ushort* Xb     = (ushort*)Yacc;  // 4 MB, aliases Yacc; dead after gemm<0>

    hipMemsetAsync(counts, 0, 256, stream);
    cast_x_kernel<<<T_TOK * DIM / 2048, 256, 0, stream>>>(x, Xb);
    router_kernel<<<T_TOK / 4, 256, 0, stream>>>(x, Wr, br, counts, tlist, wlist);
    moe_gemm<0><<<NEXP * 16 * 32, 256, 0, stream>>>(Xb, W1, b1, counts, tlist, wlist, Hbuf, nullptr);
    hipMemsetAsync(Yacc, 0, (size_t)T_TOK * DIM * sizeof(float), stream);
    moe_gemm<1><<<NEXP * 16 * 8 * 2, 256, 0, stream>>>(Hbuf, W2, b2, counts, tlist, wlist, nullptr, Yacc);
    combine_kernel<<<out_size / 1024, 256, 0, stream>>>(Yacc, out);
}